// Round 6
// baseline (165.186 us; speedup 1.0000x reference)
//
#include <hip/hip_runtime.h>
#include <hip/hip_bf16.h>
#include <cstdint>

typedef __attribute__((ext_vector_type(8))) __bf16 bf16x8;
typedef __attribute__((ext_vector_type(4))) float f32x4;
typedef __attribute__((ext_vector_type(16))) float f32x16;

#define DM 1024
#define NH 16
#define DH 64
#define S_LEN 2048
#define BATCH 2

__device__ __forceinline__ ushort f2bf(float f) {
  union { float f; uint32_t u; } v; v.f = f;
  uint32_t u = v.u;
  uint32_t r = (u + 0x7fffu + ((u >> 16) & 1u)) >> 16;
  return (ushort)r;
}
__device__ __forceinline__ float bf2f(ushort h) {
  union { uint32_t u; float f; } v; v.u = ((uint32_t)h) << 16;
  return v.f;
}

__device__ __forceinline__ void gload16(const void* g, void* l) {
  __builtin_amdgcn_global_load_lds(
      (const __attribute__((address_space(1))) unsigned*)g,
      (__attribute__((address_space(3))) unsigned*)l, 16, 0, 0);
}

__device__ __forceinline__ float tmax16(const f32x16& v) {
  float a = fmaxf(fmaxf(v[0], v[1]), fmaxf(v[2], v[3]));
  float b = fmaxf(fmaxf(v[4], v[5]), fmaxf(v[6], v[7]));
  float c = fmaxf(fmaxf(v[8], v[9]), fmaxf(v[10], v[11]));
  float d = fmaxf(fmaxf(v[12], v[13]), fmaxf(v[14], v[15]));
  return fmaxf(fmaxf(a, b), fmaxf(c, d));
}
__device__ __forceinline__ float tsum16(const f32x16& v) {
  float a = (v[0] + v[1]) + (v[2] + v[3]);
  float b = (v[4] + v[5]) + (v[6] + v[7]);
  float c = (v[8] + v[9]) + (v[10] + v[11]);
  float d = (v[12] + v[13]) + (v[14] + v[15]);
  return (a + b) + (c + d);
}

// ---------------- cast f32 -> bf16 ----------------
__global__ void cast_f32_bf16(const float* __restrict__ src, ushort* __restrict__ dst, int n4) {
  for (int i = blockIdx.x * blockDim.x + threadIdx.x; i < n4; i += gridDim.x * blockDim.x) {
    float4 v = ((const float4*)src)[i];
    ushort4 o;
    o.x = f2bf(v.x); o.y = f2bf(v.y); o.z = f2bf(v.z); o.w = f2bf(v.w);
    ((ushort4*)dst)[i] = o;
  }
}

// ---------------- GEMM v3: dbuf 2-phase + both-sides XOR swizzle (unchanged) ----------------
template<int WRITE_BF16>
__global__ __launch_bounds__(256) void gemm_bt3(
    const ushort* __restrict__ A, const ushort* __restrict__ B,
    void* __restrict__ Cv, int M, int N, int K)
{
  __shared__ ushort As[2][128][64];
  __shared__ ushort Bs[2][128][64];
  const int t = threadIdx.x;
  const int w = t >> 6, lane = t & 63;
  const int wm = w >> 1, wn = w & 1;
  const int lr = lane & 15, lk = lane >> 4;
  const int m0 = blockIdx.y * 128, n0 = blockIdx.x * 128;

  const int srow8 = lane >> 3;
  const int scol  = ((lane & 7) ^ srow8) * 8;

  f32x4 acc[4][4];
#pragma unroll
  for (int m = 0; m < 4; m++)
#pragma unroll
    for (int n = 0; n < 4; n++) acc[m][n] = (f32x4)(0.0f);

  const int nk = K >> 6;

  auto STAGE = [&](int bf, int s) {
    const int k0 = s << 6;
#pragma unroll
    for (int j = 0; j < 4; ++j) {
      const int c = w * 4 + j;
      const int row = c * 8 + srow8;
      gload16(&A[(size_t)(m0 + row) * K + k0 + scol], &As[bf][c * 8][0]);
      gload16(&B[(size_t)(n0 + row) * K + k0 + scol], &Bs[bf][c * 8][0]);
    }
  };

  STAGE(0, 0);
  __syncthreads();

  for (int s = 0; s < nk; ++s) {
    const int cur = s & 1;
    if (s + 1 < nk) STAGE(cur ^ 1, s + 1);

    bf16x8 af[4][2], bfr[4][2];
#pragma unroll
    for (int m = 0; m < 4; m++)
#pragma unroll
      for (int kk = 0; kk < 2; kk++) {
        const int ch = (((kk << 2) + lk) ^ (lr & 7)) * 8;
        af[m][kk] = *(const bf16x8*)&As[cur][wm * 64 + m * 16 + lr][ch];
      }
#pragma unroll
    for (int n = 0; n < 4; n++)
#pragma unroll
      for (int kk = 0; kk < 2; kk++) {
        const int ch = (((kk << 2) + lk) ^ (lr & 7)) * 8;
        bfr[n][kk] = *(const bf16x8*)&Bs[cur][wn * 64 + n * 16 + lr][ch];
      }

    __builtin_amdgcn_s_setprio(1);
#pragma unroll
    for (int kk = 0; kk < 2; kk++)
#pragma unroll
      for (int m = 0; m < 4; m++)
#pragma unroll
        for (int n = 0; n < 4; n++)
          acc[m][n] = __builtin_amdgcn_mfma_f32_16x16x32_bf16(af[m][kk], bfr[n][kk], acc[m][n], 0, 0, 0);
    __builtin_amdgcn_s_setprio(0);

    __syncthreads();
  }

#pragma unroll
  for (int m = 0; m < 4; m++) {
    int row = m0 + wm * 64 + m * 16 + lk * 4;
#pragma unroll
    for (int n = 0; n < 4; n++) {
      int col = n0 + wn * 64 + n * 16 + lr;
#pragma unroll
      for (int r = 0; r < 4; r++) {
        float val = acc[m][n][r];
        if (WRITE_BF16) ((ushort*)Cv)[(size_t)(row + r) * N + col] = f2bf(val);
        else            ((float*)Cv)[(size_t)(row + r) * N + col] = val;
      }
    }
  }
}

// ---------------- RoPE cos/sin table: (S, 32) float2 ----------------
__global__ void rope_table(float2* __restrict__ tab) {
  int idx = blockIdx.x * 256 + threadIdx.x;
  int i = idx & 31, s = idx >> 5;
  float inv = expf(-(float)i * (9.210340371976184f / 32.0f));
  float ang = (float)s * inv;
  float sn, cs;
  sincosf(ang, &sn, &cs);
  tab[idx] = make_float2(cs, sn);
}

// ---------------- RoPE on q,k + repack to (BH, S, 64), vectorized ----------------
__global__ void rope_qk2(const ushort* __restrict__ qkv, const float2* __restrict__ tab,
                         ushort* __restrict__ Qh, ushort* __restrict__ Kh) {
  int idx = blockIdx.x * 256 + threadIdx.x;
  int i4 = idx & 7;
  int h  = (idx >> 3) & 15;
  int s  = (idx >> 7) & 2047;
  int b  = idx >> 18;
  const size_t base = ((size_t)(b * S_LEN + s)) * 3072 + h * 64 + i4 * 8;
  uint4 qv = *(const uint4*)&qkv[base];
  uint4 kv = *(const uint4*)&qkv[base + 1024];
  const float scale = 0.125f * 1.4426950408889634f;
  uint32_t qo[4], ko[4];
  const uint32_t* qw = (const uint32_t*)&qv;
  const uint32_t* kw = (const uint32_t*)&kv;
#pragma unroll
  for (int j = 0; j < 4; ++j) {
    float2 t2 = tab[s * 32 + i4 * 4 + j];
    float qr = bf2f((ushort)(qw[j] & 0xffff)), qi = bf2f((ushort)(qw[j] >> 16));
    float kr = bf2f((ushort)(kw[j] & 0xffff)), ki = bf2f((ushort)(kw[j] >> 16));
    float oqr = (qr * t2.x - qi * t2.y) * scale, oqi = (qr * t2.y + qi * t2.x) * scale;
    float okr = kr * t2.x - ki * t2.y,           oki = kr * t2.y + ki * t2.x;
    qo[j] = (uint32_t)f2bf(oqr) | ((uint32_t)f2bf(oqi) << 16);
    ko[j] = (uint32_t)f2bf(okr) | ((uint32_t)f2bf(oki) << 16);
  }
  const size_t ob = ((size_t)((b * NH + h) * S_LEN + s)) * 64 + i4 * 8;
  *(uint4*)&Qh[ob] = *(const uint4*)qo;
  *(uint4*)&Kh[ob] = *(const uint4*)ko;
}

// ---------------- V: (b,s,h,d) slice of qkv -> Vt (BH, 64, S) ----------------
__global__ __launch_bounds__(256) void transpose_v(const ushort* __restrict__ qkv, ushort* __restrict__ Vt) {
  __shared__ ushort tile[64][72];
  int st = blockIdx.x;
  int bh = blockIdx.y;
  int b = bh >> 4, h = bh & 15;
  int t = threadIdx.x;
#pragma unroll
  for (int p = 0; p < 2; p++) {
    int c = t + p * 256;
    int srow = c >> 3;
    int d8 = (c & 7) * 8;
    *(uint4*)&tile[srow][d8] =
        *(const uint4*)&qkv[((size_t)(b * S_LEN + st * 64 + srow)) * 3072 + 2048 + h * 64 + d8];
  }
  __syncthreads();
#pragma unroll
  for (int p = 0; p < 2; p++) {
    int c = t + p * 256;
    int d = c >> 3;
    int s8 = (c & 7) * 8;
    ushort tmp[8];
#pragma unroll
    for (int j = 0; j < 8; j++) tmp[j] = tile[s8 + j][d];
    *(uint4*)&Vt[((size_t)(bh * 64 + d)) * S_LEN + st * 64 + s8] = *(uint4*)tmp;
  }
}

// ---------------- causal flash attention v4: no K/V LDS staging ----------------
// K/V are L2-resident (512 KB per head, 4 heads per XCD -> 2 MB of 4 MB L2).
// Fragments loaded directly global->VGPR; zero barriers in main loop;
// next-K register prefetch; tree-reduced softmax; T12 + T13 as before.
__global__ __launch_bounds__(128) void flash_attn4(
    const ushort* __restrict__ Qh, const ushort* __restrict__ Kh, const ushort* __restrict__ Vt,
    ushort* __restrict__ O)
{
  __shared__ __align__(16) ushort Ot[2][32][68];   // per-wave epilogue buffer

  const int bh = blockIdx.x;        // XCD = bh % 8 -> 4 heads per XCD L2
  const int qt = 31 - blockIdx.y;   // heavy q-tiles first
  const int b = bh >> 4, h = bh & 15;
  const int t = threadIdx.x;
  const int w = t >> 6, lane = t & 63;
  const int q5 = lane & 31, hi = lane >> 5;

  bf16x8 qreg[4];
  {
    const int qrow = qt * 64 + w * 32 + q5;
    const size_t qb = ((size_t)bh * S_LEN + qrow) * 64;
#pragma unroll
    for (int c = 0; c < 4; ++c)
      qreg[c] = *(const bf16x8*)&Qh[qb + c * 16 + hi * 8];
  }

  f32x16 oacc[2];
  oacc[0] = (f32x16)(0.0f); oacc[1] = (f32x16)(0.0f);
  float mrun = -1e30f, lsum = 0.0f;

  const ushort* Kg = &Kh[((size_t)bh * S_LEN) * 64];
  const ushort* Vg = &Vt[((size_t)bh * 64) * S_LEN];

  // loop-invariant per-lane element offsets
  // K-frag (kg,c): (kg*32+q5)*64 + c*16 + hi*8    [+ jt*4096]
  // V-frag (dg,kc): (dg*32+q5)*S_LEN + kc*16 + hi*8  [+ jt*64]
  bf16x8 kf[2][4];
#pragma unroll
  for (int kg = 0; kg < 2; ++kg)
#pragma unroll
    for (int c = 0; c < 4; ++c)
      kf[kg][c] = *(const bf16x8*)&Kg[(size_t)(kg * 32 + q5) * 64 + c * 16 + hi * 8];

  for (int jt = 0; jt <= qt; ++jt) {
    const ushort* Vj = Vg + (size_t)jt * 64;
    bf16x8 vf[2][4];
#pragma unroll
    for (int dg = 0; dg < 2; ++dg)
#pragma unroll
      for (int kc = 0; kc < 4; ++kc)
        vf[dg][kc] = *(const bf16x8*)&Vj[(size_t)(dg * 32 + q5) * S_LEN + kc * 16 + hi * 8];

    bf16x8 kfn[2][4];
    if (jt < qt) {
      const ushort* Kn = Kg + (size_t)(jt + 1) * 4096;
#pragma unroll
      for (int kg = 0; kg < 2; ++kg)
#pragma unroll
        for (int c = 0; c < 4; ++c)
          kfn[kg][c] = *(const bf16x8*)&Kn[(size_t)(kg * 32 + q5) * 64 + c * 16 + hi * 8];
    }

    // ---- QK^T (swapped): sc = K-frag x Q^T-frag ----
    f32x16 sc[2];
    sc[0] = (f32x16)(0.0f); sc[1] = (f32x16)(0.0f);
    __builtin_amdgcn_s_setprio(1);
#pragma unroll
    for (int kg = 0; kg < 2; ++kg)
#pragma unroll
      for (int c = 0; c < 4; ++c)
        sc[kg] = __builtin_amdgcn_mfma_f32_32x32x16_bf16(kf[kg][c], qreg[c], sc[kg], 0, 0, 0);
    __builtin_amdgcn_s_setprio(0);

    // ---- causal mask (diag tile only) ----
    if (jt == qt) {
      const int qloc = w * 32 + q5;
#pragma unroll
      for (int r = 0; r < 16; ++r) {
        const int kl = (r & 3) + 8 * (r >> 2) + 4 * hi;
        if (kl > qloc)      sc[0][r] = -1e30f;
        if (kl + 32 > qloc) sc[1][r] = -1e30f;
      }
    }

    // ---- online softmax (log2 domain), tree reductions, defer-max T13 ----
    float pmax = fmaxf(tmax16(sc[0]), tmax16(sc[1]));
    pmax = fmaxf(pmax, __shfl_xor(pmax, 32, 64));
    if (!__all(pmax - mrun <= 8.0f)) {
      const float mnew = fmaxf(mrun, pmax);
      const float alpha = __builtin_amdgcn_exp2f(mrun - mnew);
      mrun = mnew;
      lsum *= alpha;
#pragma unroll
      for (int r = 0; r < 16; ++r) { oacc[0][r] *= alpha; oacc[1][r] *= alpha; }
    }
#pragma unroll
    for (int kg = 0; kg < 2; ++kg)
#pragma unroll
      for (int r = 0; r < 16; ++r)
        sc[kg][r] = __builtin_amdgcn_exp2f(sc[kg][r] - mrun);
    float rsum = tsum16(sc[0]) + tsum16(sc[1]);
    rsum += __shfl_xor(rsum, 32, 64);
    lsum += rsum;

    // ---- P -> bf16 B-fragments in registers (T12) ----
    bf16x8 pf[4];
#pragma unroll
    for (int kc = 0; kc < 4; ++kc) {
      const int kg = kc >> 1, rA = (kc & 1) * 8, rB = rA + 4;
      uint32_t A0, A1, B0, B1;
      asm("v_cvt_pk_bf16_f32 %0, %1, %2" : "=v"(A0) : "v"(sc[kg][rA + 0]), "v"(sc[kg][rA + 1]));
      asm("v_cvt_pk_bf16_f32 %0, %1, %2" : "=v"(A1) : "v"(sc[kg][rA + 2]), "v"(sc[kg][rA + 3]));
      asm("v_cvt_pk_bf16_f32 %0, %1, %2" : "=v"(B0) : "v"(sc[kg][rB + 0]), "v"(sc[kg][rB + 1]));
      asm("v_cvt_pk_bf16_f32 %0, %1, %2" : "=v"(B1) : "v"(sc[kg][rB + 2]), "v"(sc[kg][rB + 3]));
      asm("v_permlane32_swap_b32 %0, %1" : "+v"(A0), "+v"(B0));
      asm("v_permlane32_swap_b32 %0, %1" : "+v"(A1), "+v"(B1));
      union { uint32_t u[4]; bf16x8 v; } cv;
      cv.u[0] = A0; cv.u[1] = A1; cv.u[2] = B0; cv.u[3] = B1;
      pf[kc] = cv.v;
    }

    // ---- PV: O^T += V^T-frag x P^T-frag ----
    __builtin_amdgcn_s_setprio(1);
#pragma unroll
    for (int dg = 0; dg < 2; ++dg)
#pragma unroll
      for (int kc = 0; kc < 4; ++kc)
        oacc[dg] = __builtin_amdgcn_mfma_f32_32x32x16_bf16(vf[dg][kc], pf[kc], oacc[dg], 0, 0, 0);
    __builtin_amdgcn_s_setprio(0);

    if (jt < qt) {
#pragma unroll
      for (int kg = 0; kg < 2; ++kg)
#pragma unroll
        for (int c = 0; c < 4; ++c)
          kf[kg][c] = kfn[kg][c];
    }
  }

  // ---- epilogue: O^T -> per-wave LDS transpose -> coalesced global store ----
  const float inv = 1.0f / lsum;
#pragma unroll
  for (int dg = 0; dg < 2; ++dg)
#pragma unroll
    for (int g = 0; g < 4; ++g) {
      ushort4 ok;
      ok.x = f2bf(oacc[dg][4 * g + 0] * inv); ok.y = f2bf(oacc[dg][4 * g + 1] * inv);
      ok.z = f2bf(oacc[dg][4 * g + 2] * inv); ok.w = f2bf(oacc[dg][4 * g + 3] * inv);
      *(ushort4*)&Ot[w][q5][dg * 32 + g * 8 + 4 * hi] = ok;
    }
  // each wave reads back only its own region (no cross-wave dependency)
  {
    const int row = lane >> 1, c32 = (lane & 1) * 32;
    const size_t gb = ((size_t)(b * S_LEN + qt * 64 + w * 32 + row)) * DM + h * 64 + c32;
#pragma unroll
    for (int j = 0; j < 4; ++j)
      *(uint4*)&O[gb + j * 8] = *(const uint4*)&Ot[w][row][c32 + j * 8];
  }
}

extern "C" void kernel_launch(void* const* d_in, const int* in_sizes, int n_in,
                              void* d_out, int out_size, void* d_ws, size_t ws_size,
                              hipStream_t stream) {
  const float* x     = (const float*)d_in[0];
  const float* w_qkv = (const float*)d_in[2];
  const float* w_out = (const float*)d_in[3];
  float* out = (float*)d_out;

  char* ws = (char*)d_ws;
  ushort* xb    = (ushort*)(ws);
  ushort* wqkvb = (ushort*)(ws + 8388608);
  ushort* woutb = (ushort*)(ws + 14680064);
  ushort* qkvb  = (ushort*)(ws + 16777216);
  ushort* Qh    = (ushort*)(ws + 41943040);
  ushort* Kh    = (ushort*)(ws + 50331648);
  ushort* Vt    = (ushort*)(ws + 58720256);
  ushort* Ob    = (ushort*)(ws + 67108864);
  float2* tab   = (float2*)(ws + 75497472);

  cast_f32_bf16<<<4096, 256, 0, stream>>>(x, xb, 4194304 / 4);
  cast_f32_bf16<<<3072, 256, 0, stream>>>(w_qkv, wqkvb, 3145728 / 4);
  cast_f32_bf16<<<1024, 256, 0, stream>>>(w_out, woutb, 1048576 / 4);
  rope_table<<<256, 256, 0, stream>>>(tab);

  gemm_bt3<1><<<dim3(24, 32), 256, 0, stream>>>(xb, wqkvb, qkvb, 4096, 3072, 1024);

  rope_qk2<<<2048, 256, 0, stream>>>(qkvb, tab, Qh, Kh);
  transpose_v<<<dim3(32, 32), 256, 0, stream>>>(qkvb, Vt);

  flash_attn4<<<dim3(32, 32), 128, 0, stream>>>(Qh, Kh, Vt, Ob);

  gemm_bt3<0><<<dim3(8, 32), 256, 0, stream>>>(Ob, woutb, out, 4096, 1024, 1024);
}

// Round 7
// 127.352 us; speedup vs baseline: 1.2971x; 1.2971x over previous
//
#include <hip/hip_runtime.h>
#include <hip/hip_bf16.h>
#include <cstdint>

typedef __attribute__((ext_vector_type(8))) __bf16 bf16x8;
typedef __attribute__((ext_vector_type(4))) float f32x4;
typedef __attribute__((ext_vector_type(16))) float f32x16;

#define DM 1024
#define NH 16
#define DH 64
#define S_LEN 2048
#define BATCH 2

__device__ __forceinline__ ushort f2bf(float f) {
  union { float f; uint32_t u; } v; v.f = f;
  uint32_t u = v.u;
  uint32_t r = (u + 0x7fffu + ((u >> 16) & 1u)) >> 16;
  return (ushort)r;
}
__device__ __forceinline__ float bf2f(ushort h) {
  union { uint32_t u; float f; } v; v.u = ((uint32_t)h) << 16;
  return v.f;
}

__device__ __forceinline__ void gload16(const void* g, void* l) {
  __builtin_amdgcn_global_load_lds(
      (const __attribute__((address_space(1))) unsigned*)g,
      (__attribute__((address_space(3))) unsigned*)l, 16, 0, 0);
}

// ---------------- prep: all f32->bf16 casts + rope table in one kernel ----------------
// units: [0,1048576) x cast (float4 each); [.., +786432) w_qkv; [.., +262144) w_out;
// [.., +65536) rope table entries.
__global__ void prep(const float* __restrict__ x, const float* __restrict__ wqkv,
                     const float* __restrict__ wout,
                     ushort* __restrict__ xb, ushort* __restrict__ wqkvb,
                     ushort* __restrict__ woutb, float2* __restrict__ tab) {
  const int NX = 1048576, NW = 786432, NO = 262144, NT = 65536;
  for (int i = blockIdx.x * blockDim.x + threadIdx.x; i < NX + NW + NO + NT;
       i += gridDim.x * blockDim.x) {
    if (i < NX + NW + NO) {
      const float* src; ushort* dst; int j;
      if (i < NX)           { src = x;    dst = xb;    j = i; }
      else if (i < NX + NW) { src = wqkv; dst = wqkvb; j = i - NX; }
      else                  { src = wout; dst = woutb; j = i - NX - NW; }
      float4 v = ((const float4*)src)[j];
      ushort4 o;
      o.x = f2bf(v.x); o.y = f2bf(v.y); o.z = f2bf(v.z); o.w = f2bf(v.w);
      ((ushort4*)dst)[j] = o;
    } else {
      int j = i - NX - NW - NO;
      int fi = j & 31, s = j >> 5;
      float inv = expf(-(float)fi * (9.210340371976184f / 32.0f));
      float ang = (float)s * inv;
      float sn, cs;
      sincosf(ang, &sn, &cs);
      tab[j] = make_float2(cs, sn);
    }
  }
}

// ---------------- GEMM v4: m97 single-buffer + both-sides XOR swizzle ----------------
// C[M,N] = A[M,K] * B[N,K]^T. 128x128 tile, BK=64, 4 waves (2x2), 32 KB LDS
// -> 3 blocks/CU. global_load_lds w16 staging, pre-swizzled source col
// (lane&7)^(row&7); reads apply the same involution. 2 barriers per K-step
// (m97: implicit cross-block wave overlap captures the pipelining gain).
template<int WRITE_BF16>
__global__ __launch_bounds__(256) void gemm_bt4(
    const ushort* __restrict__ A, const ushort* __restrict__ B,
    void* __restrict__ Cv, int M, int N, int K)
{
  __shared__ ushort As[128][64];   // 16 KB
  __shared__ ushort Bs[128][64];   // 16 KB
  const int t = threadIdx.x;
  const int w = t >> 6, lane = t & 63;
  const int wm = w >> 1, wn = w & 1;
  const int lr = lane & 15, lk = lane >> 4;
  const int m0 = blockIdx.y * 128, n0 = blockIdx.x * 128;

  const int srow8 = lane >> 3;                 // row within 8-row chunk
  const int scol  = ((lane & 7) ^ srow8) * 8;  // swizzled source ushort col

  f32x4 acc[4][4];
#pragma unroll
  for (int m = 0; m < 4; m++)
#pragma unroll
    for (int n = 0; n < 4; n++) acc[m][n] = (f32x4)(0.0f);

  for (int k0 = 0; k0 < K; k0 += 64) {
#pragma unroll
    for (int j = 0; j < 4; ++j) {
      const int c = w * 4 + j;                 // chunk 0..15 (8 rows x 64 ushort)
      const int row = c * 8 + srow8;
      gload16(&A[(size_t)(m0 + row) * K + k0 + scol], &As[c * 8][0]);
      gload16(&B[(size_t)(n0 + row) * K + k0 + scol], &Bs[c * 8][0]);
    }
    __syncthreads();

    bf16x8 af[4][2], bfr[4][2];
#pragma unroll
    for (int m = 0; m < 4; m++)
#pragma unroll
      for (int kk = 0; kk < 2; kk++) {
        const int ch = (((kk << 2) + lk) ^ (lr & 7)) * 8;   // swizzled read col
        af[m][kk] = *(const bf16x8*)&As[wm * 64 + m * 16 + lr][ch];
      }
#pragma unroll
    for (int n = 0; n < 4; n++)
#pragma unroll
      for (int kk = 0; kk < 2; kk++) {
        const int ch = (((kk << 2) + lk) ^ (lr & 7)) * 8;
        bfr[n][kk] = *(const bf16x8*)&Bs[wn * 64 + n * 16 + lr][ch];
      }

    __builtin_amdgcn_s_setprio(1);
#pragma unroll
    for (int kk = 0; kk < 2; kk++)
#pragma unroll
      for (int m = 0; m < 4; m++)
#pragma unroll
        for (int n = 0; n < 4; n++)
          acc[m][n] = __builtin_amdgcn_mfma_f32_16x16x32_bf16(af[m][kk], bfr[n][kk], acc[m][n], 0, 0, 0);
    __builtin_amdgcn_s_setprio(0);

    __syncthreads();
  }

#pragma unroll
  for (int m = 0; m < 4; m++) {
    int row = m0 + wm * 64 + m * 16 + lk * 4;
#pragma unroll
    for (int n = 0; n < 4; n++) {
      int col = n0 + wn * 64 + n * 16 + lr;
#pragma unroll
      for (int r = 0; r < 4; r++) {
        float val = acc[m][n][r];
        if (WRITE_BF16) ((ushort*)Cv)[(size_t)(row + r) * N + col] = f2bf(val);
        else            ((float*)Cv)[(size_t)(row + r) * N + col] = val;
      }
    }
  }
}

// ---------------- RoPE on q,k + repack to (BH, S, 64), vectorized ----------------
// Q scale = D^-0.5 * log2(e): softmax runs in log2 domain downstream.
__global__ void rope_qk2(const ushort* __restrict__ qkv, const float2* __restrict__ tab,
                         ushort* __restrict__ Qh, ushort* __restrict__ Kh) {
  int idx = blockIdx.x * 256 + threadIdx.x;
  int i4 = idx & 7;
  int h  = (idx >> 3) & 15;
  int s  = (idx >> 7) & 2047;
  int b  = idx >> 18;
  const size_t base = ((size_t)(b * S_LEN + s)) * 3072 + h * 64 + i4 * 8;
  uint4 qv = *(const uint4*)&qkv[base];
  uint4 kv = *(const uint4*)&qkv[base + 1024];
  const float scale = 0.125f * 1.4426950408889634f;
  uint32_t qo[4], ko[4];
  const uint32_t* qw = (const uint32_t*)&qv;
  const uint32_t* kw = (const uint32_t*)&kv;
#pragma unroll
  for (int j = 0; j < 4; ++j) {
    float2 t2 = tab[s * 32 + i4 * 4 + j];
    float qr = bf2f((ushort)(qw[j] & 0xffff)), qi = bf2f((ushort)(qw[j] >> 16));
    float kr = bf2f((ushort)(kw[j] & 0xffff)), ki = bf2f((ushort)(kw[j] >> 16));
    float oqr = (qr * t2.x - qi * t2.y) * scale, oqi = (qr * t2.y + qi * t2.x) * scale;
    float okr = kr * t2.x - ki * t2.y,           oki = kr * t2.y + ki * t2.x;
    qo[j] = (uint32_t)f2bf(oqr) | ((uint32_t)f2bf(oqi) << 16);
    ko[j] = (uint32_t)f2bf(okr) | ((uint32_t)f2bf(oki) << 16);
  }
  const size_t ob = ((size_t)((b * NH + h) * S_LEN + s)) * 64 + i4 * 8;
  *(uint4*)&Qh[ob] = *(const uint4*)qo;
  *(uint4*)&Kh[ob] = *(const uint4*)ko;
}

// ---------------- V: (b,s,h,d) slice of qkv -> Vt (BH, 64, S) ----------------
__global__ __launch_bounds__(256) void transpose_v(const ushort* __restrict__ qkv, ushort* __restrict__ Vt) {
  __shared__ ushort tile[64][72];
  int st = blockIdx.x;
  int bh = blockIdx.y;
  int b = bh >> 4, h = bh & 15;
  int t = threadIdx.x;
#pragma unroll
  for (int p = 0; p < 2; p++) {
    int c = t + p * 256;
    int srow = c >> 3;
    int d8 = (c & 7) * 8;
    *(uint4*)&tile[srow][d8] =
        *(const uint4*)&qkv[((size_t)(b * S_LEN + st * 64 + srow)) * 3072 + 2048 + h * 64 + d8];
  }
  __syncthreads();
#pragma unroll
  for (int p = 0; p < 2; p++) {
    int c = t + p * 256;
    int d = c >> 3;
    int s8 = (c & 7) * 8;
    ushort tmp[8];
#pragma unroll
    for (int j = 0; j < 8; j++) tmp[j] = tile[s8 + j][d];
    *(uint4*)&Vt[((size_t)(bh * 64 + d)) * S_LEN + st * 64 + s8] = *(uint4*)tmp;
  }
}

// ---------------- causal flash attention v3 (reverted to R5 exact) ----------------
union SMemU {
  struct { ushort K[2][64][64]; ushort V[2][64][64]; } kv;  // 32 KB
  ushort Ot[64][68];
};

__global__ __launch_bounds__(128) void flash_attn3(
    const ushort* __restrict__ Qh, const ushort* __restrict__ Kh, const ushort* __restrict__ Vt,
    ushort* __restrict__ O)
{
  __shared__ __align__(16) SMemU sm;

  const int bh = blockIdx.x;
  const int qt = 31 - blockIdx.y;
  const int b = bh >> 4, h = bh & 15;
  const int t = threadIdx.x;
  const int w = t >> 6, lane = t & 63;
  const int q5 = lane & 31, hi = lane >> 5;

  bf16x8 qreg[4];
  {
    const int qrow = qt * 64 + w * 32 + q5;
    const size_t qb = ((size_t)bh * S_LEN + qrow) * 64;
#pragma unroll
    for (int c = 0; c < 4; ++c)
      qreg[c] = *(const bf16x8*)&Qh[qb + c * 16 + hi * 8];
  }

  f32x16 oacc[2];
  oacc[0] = (f32x16)(0.0f); oacc[1] = (f32x16)(0.0f);
  float mrun = -1e30f, lsum = 0.0f;

  const ushort* Kg = &Kh[((size_t)bh * S_LEN) * 64];
  const ushort* Vg = &Vt[((size_t)bh * 64) * S_LEN];

  auto STAGE = [&](int bf, int jt) {
#pragma unroll
    for (int p = 0; p < 4; ++p) {
      int row = w * 32 + p * 8 + (lane >> 3);
      int c16 = (lane & 7) ^ (row & 7);
      gload16(&Kg[((size_t)(jt * 64 + row)) * 64 + c16 * 8], &sm.kv.K[bf][w * 32 + p * 8][0]);
      gload16(&Vg[((size_t)row) * S_LEN + jt * 64 + c16 * 8], &sm.kv.V[bf][w * 32 + p * 8][0]);
    }
  };

  STAGE(0, 0);
  __syncthreads();

  int cur = 0;
  for (int jt = 0; jt <= qt; ++jt) {
    if (jt < qt) STAGE(cur ^ 1, jt + 1);

    f32x16 sc[2];
    sc[0] = (f32x16)(0.0f); sc[1] = (f32x16)(0.0f);
    __builtin_amdgcn_s_setprio(1);
#pragma unroll
    for (int kg = 0; kg < 2; ++kg) {
      const int kr = kg * 32 + q5;
#pragma unroll
      for (int c = 0; c < 4; ++c) {
        bf16x8 kf = *(const bf16x8*)&sm.kv.K[cur][kr][((c * 2 + hi) ^ (kr & 7)) * 8];
        sc[kg] = __builtin_amdgcn_mfma_f32_32x32x16_bf16(kf, qreg[c], sc[kg], 0, 0, 0);
      }
    }
    __builtin_amdgcn_s_setprio(0);

    if (jt == qt) {
      const int qloc = w * 32 + q5;
#pragma unroll
      for (int r = 0; r < 16; ++r) {
        const int kl = (r & 3) + 8 * (r >> 2) + 4 * hi;
        if (kl > qloc)      sc[0][r] = -1e30f;
        if (kl + 32 > qloc) sc[1][r] = -1e30f;
      }
    }

    float pmax = -1e30f;
#pragma unroll
    for (int r = 0; r < 16; ++r) { pmax = fmaxf(pmax, sc[0][r]); pmax = fmaxf(pmax, sc[1][r]); }
    pmax = fmaxf(pmax, __shfl_xor(pmax, 32, 64));
    if (!__all(pmax - mrun <= 8.0f)) {
      const float mnew = fmaxf(mrun, pmax);
      const float alpha = __builtin_amdgcn_exp2f(mrun - mnew);
      mrun = mnew;
      lsum *= alpha;
#pragma unroll
      for (int r = 0; r < 16; ++r) { oacc[0][r] *= alpha; oacc[1][r] *= alpha; }
    }
    float rsum = 0.0f;
#pragma unroll
    for (int kg = 0; kg < 2; ++kg)
#pragma unroll
      for (int r = 0; r < 16; ++r) {
        sc[kg][r] = __builtin_amdgcn_exp2f(sc[kg][r] - mrun);
        rsum += sc[kg][r];
      }
    rsum += __shfl_xor(rsum, 32, 64);
    lsum += rsum;

    bf16x8 pf[4];
#pragma unroll
    for (int kc = 0; kc < 4; ++kc) {
      const int kg = kc >> 1, rA = (kc & 1) * 8, rB = rA + 4;
      uint32_t A0, A1, B0, B1;
      asm("v_cvt_pk_bf16_f32 %0, %1, %2" : "=v"(A0) : "v"(sc[kg][rA + 0]), "v"(sc[kg][rA + 1]));
      asm("v_cvt_pk_bf16_f32 %0, %1, %2" : "=v"(A1) : "v"(sc[kg][rA + 2]), "v"(sc[kg][rA + 3]));
      asm("v_cvt_pk_bf16_f32 %0, %1, %2" : "=v"(B0) : "v"(sc[kg][rB + 0]), "v"(sc[kg][rB + 1]));
      asm("v_cvt_pk_bf16_f32 %0, %1, %2" : "=v"(B1) : "v"(sc[kg][rB + 2]), "v"(sc[kg][rB + 3]));
      asm("v_permlane32_swap_b32 %0, %1" : "+v"(A0), "+v"(B0));
      asm("v_permlane32_swap_b32 %0, %1" : "+v"(A1), "+v"(B1));
      union { uint32_t u[4]; bf16x8 v; } cv;
      cv.u[0] = A0; cv.u[1] = A1; cv.u[2] = B0; cv.u[3] = B1;
      pf[kc] = cv.v;
    }

    __builtin_amdgcn_s_setprio(1);
#pragma unroll
    for (int dg = 0; dg < 2; ++dg) {
      const int vr = dg * 32 + q5;
#pragma unroll
      for (int kc = 0; kc < 4; ++kc) {
        bf16x8 vf = *(const bf16x8*)&sm.kv.V[cur][vr][((kc * 2 + hi) ^ (vr & 7)) * 8];
        oacc[dg] = __builtin_amdgcn_mfma_f32_32x32x16_bf16(vf, pf[kc], oacc[dg], 0, 0, 0);
      }
    }
    __builtin_amdgcn_s_setprio(0);

    __syncthreads();
    cur ^= 1;
  }

  const float inv = 1.0f / lsum;
#pragma unroll
  for (int dg = 0; dg < 2; ++dg)
#pragma unroll
    for (int g = 0; g < 4; ++g) {
      ushort4 ok;
      ok.x = f2bf(oacc[dg][4 * g + 0] * inv); ok.y = f2bf(oacc[dg][4 * g + 1] * inv);
      ok.z = f2bf(oacc[dg][4 * g + 2] * inv); ok.w = f2bf(oacc[dg][4 * g + 3] * inv);
      *(ushort4*)&sm.Ot[w * 32 + q5][dg * 32 + g * 8 + 4 * hi] = ok;
    }
  __syncthreads();
  {
    const int row = t >> 1, c32 = (t & 1) * 32;
    const size_t gb = ((size_t)(b * S_LEN + qt * 64 + row)) * DM + h * 64 + c32;
#pragma unroll
    for (int j = 0; j < 4; ++j)
      *(uint4*)&O[gb + j * 8] = *(const uint4*)&sm.Ot[row][c32 + j * 8];
  }
}

extern "C" void kernel_launch(void* const* d_in, const int* in_sizes, int n_in,
                              void* d_out, int out_size, void* d_ws, size_t ws_size,
                              hipStream_t stream) {
  const float* x     = (const float*)d_in[0];
  const float* w_qkv = (const float*)d_in[2];
  const float* w_out = (const float*)d_in[3];
  float* out = (float*)d_out;

  char* ws = (char*)d_ws;
  ushort* xb    = (ushort*)(ws);
  ushort* wqkvb = (ushort*)(ws + 8388608);
  ushort* woutb = (ushort*)(ws + 14680064);
  ushort* qkvb  = (ushort*)(ws + 16777216);
  ushort* Qh    = (ushort*)(ws + 41943040);
  ushort* Kh    = (ushort*)(ws + 50331648);
  ushort* Vt    = (ushort*)(ws + 58720256);
  ushort* Ob    = (ushort*)(ws + 67108864);
  float2* tab   = (float2*)(ws + 75497472);

  prep<<<2048, 256, 0, stream>>>(x, w_qkv, w_out, xb, wqkvb, woutb, tab);

  gemm_bt4<1><<<dim3(24, 32), 256, 0, stream>>>(xb, wqkvb, qkvb, 4096, 3072, 1024);

  rope_qk2<<<2048, 256, 0, stream>>>(qkvb, tab, Qh, Kh);
  transpose_v<<<dim3(32, 32), 256, 0, stream>>>(qkvb, Vt);

  flash_attn3<<<dim3(32, 32), 128, 0, stream>>>(Qh, Kh, Vt, Ob);

  gemm_bt4<0><<<dim3(8, 32), 256, 0, stream>>>(Ob, woutb, out, 4096, 1024, 1024);
}

// Round 8
// 124.965 us; speedup vs baseline: 1.3219x; 1.0191x over previous
//
#include <hip/hip_runtime.h>
#include <hip/hip_bf16.h>
#include <cstdint>

typedef __attribute__((ext_vector_type(8))) __bf16 bf16x8;
typedef __attribute__((ext_vector_type(4))) float f32x4;
typedef __attribute__((ext_vector_type(16))) float f32x16;

#define DM 1024
#define NH 16
#define DH 64
#define S_LEN 2048
#define BATCH 2

__device__ __forceinline__ ushort f2bf(float f) {
  union { float f; uint32_t u; } v; v.f = f;
  uint32_t u = v.u;
  uint32_t r = (u + 0x7fffu + ((u >> 16) & 1u)) >> 16;
  return (ushort)r;
}
__device__ __forceinline__ float bf2f(ushort h) {
  union { uint32_t u; float f; } v; v.u = ((uint32_t)h) << 16;
  return v.f;
}

__device__ __forceinline__ void gload16(const void* g, void* l) {
  __builtin_amdgcn_global_load_lds(
      (const __attribute__((address_space(1))) unsigned*)g,
      (__attribute__((address_space(3))) unsigned*)l, 16, 0, 0);
}

__device__ __forceinline__ float tmax16(const f32x16& v) {
  float a = fmaxf(fmaxf(v[0], v[1]), fmaxf(v[2], v[3]));
  float b = fmaxf(fmaxf(v[4], v[5]), fmaxf(v[6], v[7]));
  float c = fmaxf(fmaxf(v[8], v[9]), fmaxf(v[10], v[11]));
  float d = fmaxf(fmaxf(v[12], v[13]), fmaxf(v[14], v[15]));
  return fmaxf(fmaxf(a, b), fmaxf(c, d));
}
__device__ __forceinline__ float tsum16(const f32x16& v) {
  float a = (v[0] + v[1]) + (v[2] + v[3]);
  float b = (v[4] + v[5]) + (v[6] + v[7]);
  float c = (v[8] + v[9]) + (v[10] + v[11]);
  float d = (v[12] + v[13]) + (v[14] + v[15]);
  return (a + b) + (c + d);
}

// ---------------- prep: all f32->bf16 casts + rope table in one kernel ----------------
__global__ void prep(const float* __restrict__ x, const float* __restrict__ wqkv,
                     const float* __restrict__ wout,
                     ushort* __restrict__ xb, ushort* __restrict__ wqkvb,
                     ushort* __restrict__ woutb, float2* __restrict__ tab) {
  const int NX = 1048576, NW = 786432, NO = 262144, NT = 65536;
  for (int i = blockIdx.x * blockDim.x + threadIdx.x; i < NX + NW + NO + NT;
       i += gridDim.x * blockDim.x) {
    if (i < NX + NW + NO) {
      const float* src; ushort* dst; int j;
      if (i < NX)           { src = x;    dst = xb;    j = i; }
      else if (i < NX + NW) { src = wqkv; dst = wqkvb; j = i - NX; }
      else                  { src = wout; dst = woutb; j = i - NX - NW; }
      float4 v = ((const float4*)src)[j];
      ushort4 o;
      o.x = f2bf(v.x); o.y = f2bf(v.y); o.z = f2bf(v.z); o.w = f2bf(v.w);
      ((ushort4*)dst)[j] = o;
    } else {
      int j = i - NX - NW - NO;
      int fi = j & 31, s = j >> 5;
      float inv = expf(-(float)fi * (9.210340371976184f / 32.0f));
      float ang = (float)s * inv;
      float sn, cs;
      sincosf(ang, &sn, &cs);
      tab[j] = make_float2(cs, sn);
    }
  }
}

// ---------------- GEMM v4: m97 single-buffer + both-sides XOR swizzle (unchanged) ----------------
template<int WRITE_BF16>
__global__ __launch_bounds__(256) void gemm_bt4(
    const ushort* __restrict__ A, const ushort* __restrict__ B,
    void* __restrict__ Cv, int M, int N, int K)
{
  __shared__ ushort As[128][64];
  __shared__ ushort Bs[128][64];
  const int t = threadIdx.x;
  const int w = t >> 6, lane = t & 63;
  const int wm = w >> 1, wn = w & 1;
  const int lr = lane & 15, lk = lane >> 4;
  const int m0 = blockIdx.y * 128, n0 = blockIdx.x * 128;

  const int srow8 = lane >> 3;
  const int scol  = ((lane & 7) ^ srow8) * 8;

  f32x4 acc[4][4];
#pragma unroll
  for (int m = 0; m < 4; m++)
#pragma unroll
    for (int n = 0; n < 4; n++) acc[m][n] = (f32x4)(0.0f);

  for (int k0 = 0; k0 < K; k0 += 64) {
#pragma unroll
    for (int j = 0; j < 4; ++j) {
      const int c = w * 4 + j;
      const int row = c * 8 + srow8;
      gload16(&A[(size_t)(m0 + row) * K + k0 + scol], &As[c * 8][0]);
      gload16(&B[(size_t)(n0 + row) * K + k0 + scol], &Bs[c * 8][0]);
    }
    __syncthreads();

    bf16x8 af[4][2], bfr[4][2];
#pragma unroll
    for (int m = 0; m < 4; m++)
#pragma unroll
      for (int kk = 0; kk < 2; kk++) {
        const int ch = (((kk << 2) + lk) ^ (lr & 7)) * 8;
        af[m][kk] = *(const bf16x8*)&As[wm * 64 + m * 16 + lr][ch];
      }
#pragma unroll
    for (int n = 0; n < 4; n++)
#pragma unroll
      for (int kk = 0; kk < 2; kk++) {
        const int ch = (((kk << 2) + lk) ^ (lr & 7)) * 8;
        bfr[n][kk] = *(const bf16x8*)&Bs[wn * 64 + n * 16 + lr][ch];
      }

    __builtin_amdgcn_s_setprio(1);
#pragma unroll
    for (int kk = 0; kk < 2; kk++)
#pragma unroll
      for (int m = 0; m < 4; m++)
#pragma unroll
        for (int n = 0; n < 4; n++)
          acc[m][n] = __builtin_amdgcn_mfma_f32_16x16x32_bf16(af[m][kk], bfr[n][kk], acc[m][n], 0, 0, 0);
    __builtin_amdgcn_s_setprio(0);

    __syncthreads();
  }

#pragma unroll
  for (int m = 0; m < 4; m++) {
    int row = m0 + wm * 64 + m * 16 + lk * 4;
#pragma unroll
    for (int n = 0; n < 4; n++) {
      int col = n0 + wn * 64 + n * 16 + lr;
#pragma unroll
      for (int r = 0; r < 4; r++) {
        float val = acc[m][n][r];
        if (WRITE_BF16) ((ushort*)Cv)[(size_t)(row + r) * N + col] = f2bf(val);
        else            ((float*)Cv)[(size_t)(row + r) * N + col] = val;
      }
    }
  }
}

// ---------------- RoPE on q,k + repack to (BH, S, 64), vectorized ----------------
__global__ void rope_qk2(const ushort* __restrict__ qkv, const float2* __restrict__ tab,
                         ushort* __restrict__ Qh, ushort* __restrict__ Kh) {
  int idx = blockIdx.x * 256 + threadIdx.x;
  int i4 = idx & 7;
  int h  = (idx >> 3) & 15;
  int s  = (idx >> 7) & 2047;
  int b  = idx >> 18;
  const size_t base = ((size_t)(b * S_LEN + s)) * 3072 + h * 64 + i4 * 8;
  uint4 qv = *(const uint4*)&qkv[base];
  uint4 kv = *(const uint4*)&qkv[base + 1024];
  const float scale = 0.125f * 1.4426950408889634f;
  uint32_t qo[4], ko[4];
  const uint32_t* qw = (const uint32_t*)&qv;
  const uint32_t* kw = (const uint32_t*)&kv;
#pragma unroll
  for (int j = 0; j < 4; ++j) {
    float2 t2 = tab[s * 32 + i4 * 4 + j];
    float qr = bf2f((ushort)(qw[j] & 0xffff)), qi = bf2f((ushort)(qw[j] >> 16));
    float kr = bf2f((ushort)(kw[j] & 0xffff)), ki = bf2f((ushort)(kw[j] >> 16));
    float oqr = (qr * t2.x - qi * t2.y) * scale, oqi = (qr * t2.y + qi * t2.x) * scale;
    float okr = kr * t2.x - ki * t2.y,           oki = kr * t2.y + ki * t2.x;
    qo[j] = (uint32_t)f2bf(oqr) | ((uint32_t)f2bf(oqi) << 16);
    ko[j] = (uint32_t)f2bf(okr) | ((uint32_t)f2bf(oki) << 16);
  }
  const size_t ob = ((size_t)((b * NH + h) * S_LEN + s)) * 64 + i4 * 8;
  *(uint4*)&Qh[ob] = *(const uint4*)qo;
  *(uint4*)&Kh[ob] = *(const uint4*)ko;
}

// ---------------- V: (b,s,h,d) slice of qkv -> Vt (BH, 64, S) ----------------
__global__ __launch_bounds__(256) void transpose_v(const ushort* __restrict__ qkv, ushort* __restrict__ Vt) {
  __shared__ ushort tile[64][72];
  int st = blockIdx.x;
  int bh = blockIdx.y;
  int b = bh >> 4, h = bh & 15;
  int t = threadIdx.x;
#pragma unroll
  for (int p = 0; p < 2; p++) {
    int c = t + p * 256;
    int srow = c >> 3;
    int d8 = (c & 7) * 8;
    *(uint4*)&tile[srow][d8] =
        *(const uint4*)&qkv[((size_t)(b * S_LEN + st * 64 + srow)) * 3072 + 2048 + h * 64 + d8];
  }
  __syncthreads();
#pragma unroll
  for (int p = 0; p < 2; p++) {
    int c = t + p * 256;
    int d = c >> 3;
    int s8 = (c & 7) * 8;
    ushort tmp[8];
#pragma unroll
    for (int j = 0; j < 8; j++) tmp[j] = tile[s8 + j][d];
    *(uint4*)&Vt[((size_t)(bh * 64 + d)) * S_LEN + st * 64 + s8] = *(uint4*)tmp;
  }
}

// ---------------- causal flash attention v5 ----------------
// 4 waves/block (256 thr), 128 q-rows/block (32/wave), KVBLK=64, dbuf 32 KB.
// Staging shared by 4 waves (4 gload16/thread/iter). Tree reductions.
// Full-mask iteration skip (wave-uniform). Balanced qt pairing in grid.
union SMemU {
  struct { ushort K[2][64][64]; ushort V[2][64][64]; } kv;  // 32 KB
  ushort Ot[128][68];                                       // 17.4 KB epilogue alias
};

__global__ __launch_bounds__(256) void flash_attn5(
    const ushort* __restrict__ Qh, const ushort* __restrict__ Kh, const ushort* __restrict__ Vt,
    ushort* __restrict__ O)
{
  __shared__ __align__(16) SMemU sm;

  const int bh = blockIdx.x;               // XCD = bh % 8
  const int y = blockIdx.y;
  const int qt = (y < 8) ? (15 - y) : (y - 8);   // balanced heavy/light pairing
  const int b = bh >> 4, h = bh & 15;
  const int t = threadIdx.x;
  const int w = t >> 6, lane = t & 63;
  const int q5 = lane & 31, hi = lane >> 5;

  const int qbase_w = qt * 128 + w * 32;   // global first q-row of this wave
  const int qg = qbase_w + q5;             // this lane's q-column (global)

  bf16x8 qreg[4];
  {
    const size_t qb = ((size_t)bh * S_LEN + qg) * 64;
#pragma unroll
    for (int c = 0; c < 4; ++c)
      qreg[c] = *(const bf16x8*)&Qh[qb + c * 16 + hi * 8];
  }

  f32x16 oacc[2];
  oacc[0] = (f32x16)(0.0f); oacc[1] = (f32x16)(0.0f);
  float mrun = -1e30f, lsum = 0.0f;

  const ushort* Kg = &Kh[((size_t)bh * S_LEN) * 64];
  const ushort* Vg = &Vt[((size_t)bh * 64) * S_LEN];

  // 256-thread STAGE: each thread 2 K-chunks + 2 V-chunks (16B each)
  auto STAGE = [&](int bf, int jt) {
#pragma unroll
    for (int p = 0; p < 2; ++p) {
      const int row = w * 16 + p * 8 + (lane >> 3);
      const int c16 = (lane & 7) ^ (row & 7);
      gload16(&Kg[((size_t)(jt * 64 + row)) * 64 + c16 * 8], &sm.kv.K[bf][w * 16 + p * 8][0]);
      gload16(&Vg[((size_t)row) * S_LEN + jt * 64 + c16 * 8], &sm.kv.V[bf][w * 16 + p * 8][0]);
    }
  };

  STAGE(0, 0);
  __syncthreads();

  const int njt = 2 * qt + 2;
  int cur = 0;
  for (int jt = 0; jt < njt; ++jt) {
    if (jt + 1 < njt) STAGE(cur ^ 1, jt + 1);

    const bool active = (jt * 64 <= qbase_w + 31);   // wave-uniform
    if (active) {
      // ---- QK^T (swapped): sc = K-frag x Q^T-frag ----
      f32x16 sc[2];
      sc[0] = (f32x16)(0.0f); sc[1] = (f32x16)(0.0f);
      __builtin_amdgcn_s_setprio(1);
#pragma unroll
      for (int kg = 0; kg < 2; ++kg) {
        const int kr = kg * 32 + q5;
#pragma unroll
        for (int c = 0; c < 4; ++c) {
          bf16x8 kf = *(const bf16x8*)&sm.kv.K[cur][kr][((c * 2 + hi) ^ (kr & 7)) * 8];
          sc[kg] = __builtin_amdgcn_mfma_f32_32x32x16_bf16(kf, qreg[c], sc[kg], 0, 0, 0);
        }
      }
      __builtin_amdgcn_s_setprio(0);

      // ---- causal mask (partial tiles only) ----
      if (jt * 64 + 63 > qbase_w) {
        const int kb = jt * 64;
#pragma unroll
        for (int r = 0; r < 16; ++r) {
          const int kl = kb + (r & 3) + 8 * (r >> 2) + 4 * hi;
          if (kl > qg)      sc[0][r] = -1e30f;
          if (kl + 32 > qg) sc[1][r] = -1e30f;
        }
      }

      // ---- online softmax (log2 domain), tree reductions, defer-max ----
      float pmax = fmaxf(tmax16(sc[0]), tmax16(sc[1]));
      pmax = fmaxf(pmax, __shfl_xor(pmax, 32, 64));
      if (!__all(pmax - mrun <= 8.0f)) {
        const float mnew = fmaxf(mrun, pmax);
        const float alpha = __builtin_amdgcn_exp2f(mrun - mnew);
        mrun = mnew;
        lsum *= alpha;
#pragma unroll
        for (int r = 0; r < 16; ++r) { oacc[0][r] *= alpha; oacc[1][r] *= alpha; }
      }
#pragma unroll
      for (int kg = 0; kg < 2; ++kg)
#pragma unroll
        for (int r = 0; r < 16; ++r)
          sc[kg][r] = __builtin_amdgcn_exp2f(sc[kg][r] - mrun);
      float rsum = tsum16(sc[0]) + tsum16(sc[1]);
      rsum += __shfl_xor(rsum, 32, 64);
      lsum += rsum;

      // ---- P -> bf16 B-fragments in registers (T12) ----
      bf16x8 pf[4];
#pragma unroll
      for (int kc = 0; kc < 4; ++kc) {
        const int kg = kc >> 1, rA = (kc & 1) * 8, rB = rA + 4;
        uint32_t A0, A1, B0, B1;
        asm("v_cvt_pk_bf16_f32 %0, %1, %2" : "=v"(A0) : "v"(sc[kg][rA + 0]), "v"(sc[kg][rA + 1]));
        asm("v_cvt_pk_bf16_f32 %0, %1, %2" : "=v"(A1) : "v"(sc[kg][rA + 2]), "v"(sc[kg][rA + 3]));
        asm("v_cvt_pk_bf16_f32 %0, %1, %2" : "=v"(B0) : "v"(sc[kg][rB + 0]), "v"(sc[kg][rB + 1]));
        asm("v_cvt_pk_bf16_f32 %0, %1, %2" : "=v"(B1) : "v"(sc[kg][rB + 2]), "v"(sc[kg][rB + 3]));
        asm("v_permlane32_swap_b32 %0, %1" : "+v"(A0), "+v"(B0));
        asm("v_permlane32_swap_b32 %0, %1" : "+v"(A1), "+v"(B1));
        union { uint32_t u[4]; bf16x8 v; } cv;
        cv.u[0] = A0; cv.u[1] = A1; cv.u[2] = B0; cv.u[3] = B1;
        pf[kc] = cv.v;
      }

      // ---- PV: O^T += V^T-frag x P^T-frag ----
      __builtin_amdgcn_s_setprio(1);
#pragma unroll
      for (int dg = 0; dg < 2; ++dg) {
        const int vr = dg * 32 + q5;
#pragma unroll
        for (int kc = 0; kc < 4; ++kc) {
          bf16x8 vf = *(const bf16x8*)&sm.kv.V[cur][vr][((kc * 2 + hi) ^ (vr & 7)) * 8];
          oacc[dg] = __builtin_amdgcn_mfma_f32_32x32x16_bf16(vf, pf[kc], oacc[dg], 0, 0, 0);
        }
      }
      __builtin_amdgcn_s_setprio(0);
    }

    __syncthreads();
    cur ^= 1;
  }

  // ---- epilogue: O^T -> LDS transpose -> coalesced global store ----
  const float inv = 1.0f / lsum;
#pragma unroll
  for (int dg = 0; dg < 2; ++dg)
#pragma unroll
    for (int g = 0; g < 4; ++g) {
      ushort4 ok;
      ok.x = f2bf(oacc[dg][4 * g + 0] * inv); ok.y = f2bf(oacc[dg][4 * g + 1] * inv);
      ok.z = f2bf(oacc[dg][4 * g + 2] * inv); ok.w = f2bf(oacc[dg][4 * g + 3] * inv);
      *(ushort4*)&sm.Ot[w * 32 + q5][dg * 32 + g * 8 + 4 * hi] = ok;
    }
  __syncthreads();
  {
    const int row = t >> 1, c32 = (t & 1) * 32;
    const size_t gb = ((size_t)(b * S_LEN + qt * 128 + row)) * DM + h * 64 + c32;
#pragma unroll
    for (int j = 0; j < 4; ++j)
      *(uint4*)&O[gb + j * 8] = *(const uint4*)&sm.Ot[row][c32 + j * 8];
  }
}

extern "C" void kernel_launch(void* const* d_in, const int* in_sizes, int n_in,
                              void* d_out, int out_size, void* d_ws, size_t ws_size,
                              hipStream_t stream) {
  const float* x     = (const float*)d_in[0];
  const float* w_qkv = (const float*)d_in[2];
  const float* w_out = (const float*)d_in[3];
  float* out = (float*)d_out;

  char* ws = (char*)d_ws;
  ushort* xb    = (ushort*)(ws);
  ushort* wqkvb = (ushort*)(ws + 8388608);
  ushort* woutb = (ushort*)(ws + 14680064);
  ushort* qkvb  = (ushort*)(ws + 16777216);
  ushort* Qh    = (ushort*)(ws + 41943040);
  ushort* Kh    = (ushort*)(ws + 50331648);
  ushort* Vt    = (ushort*)(ws + 58720256);
  ushort* Ob    = (ushort*)(ws + 67108864);
  float2* tab   = (float2*)(ws + 75497472);

  prep<<<2048, 256, 0, stream>>>(x, w_qkv, w_out, xb, wqkvb, woutb, tab);

  gemm_bt4<1><<<dim3(24, 32), 256, 0, stream>>>(xb, wqkvb, qkvb, 4096, 3072, 1024);

  rope_qk2<<<2048, 256, 0, stream>>>(qkvb, tab, Qh, Kh);
  transpose_v<<<dim3(32, 32), 256, 0, stream>>>(qkvb, Vt);

  // grid: x = bh (32), y = 16 (qt pairing: 15-y for y<8, y-8 for y>=8)
  flash_attn5<<<dim3(32, 16), 256, 0, stream>>>(Qh, Kh, Vt, Ob);

  gemm_bt4<0><<<dim3(8, 32), 256, 0, stream>>>(Ob, woutb, out, 4096, 1024, 1024);
}